// Round 4
// baseline (1927.959 us; speedup 1.0000x reference)
//
#include <hip/hip_runtime.h>
#include <math.h>

#define N_NODES 50000
#define N_EDGES 500000

using bf16x8 = __attribute__((ext_vector_type(8))) short;
using f32x4  = __attribute__((ext_vector_type(4))) float;

// ---------- bf16 helpers ----------
__device__ inline float b2f(unsigned short u) {
  union { unsigned int i; float f; } v; v.i = ((unsigned int)u) << 16; return v.f;
}
__device__ inline unsigned short f2b(float f) {
  union { float f; unsigned int i; } v; v.f = f;
  unsigned int x = v.i;
  return (unsigned short)((x + 0x7fffu + ((x >> 16) & 1u)) >> 16);
}
__device__ inline void stv(unsigned short* p, float v) { *p = f2b(v); }
__device__ inline void stv(float* p, float v) { *p = v; }
__device__ inline float ldf(unsigned short u) { return b2f(u); }
__device__ inline float ldf(float f) { return f; }

// ---------------- degree / CSR ----------------
__global__ void k_count(const int* __restrict__ src, const int* __restrict__ dst,
                        int* __restrict__ cnt, int* __restrict__ degall) {
  int e = blockIdx.x * blockDim.x + threadIdx.x;
  if (e < N_EDGES) {
    atomicAdd(&cnt[dst[e]], 1);
    atomicAdd(&degall[src[e]], 1);
    atomicAdd(&degall[dst[e]], 1);
  }
}

__global__ __launch_bounds__(1024) void k_scan(const int* __restrict__ cnt, int* __restrict__ ptr) {
  __shared__ int buf[1024];
  __shared__ int carry;
  if (threadIdx.x == 0) carry = 0;
  __syncthreads();
  for (int base = 0; base < N_NODES; base += 1024) {
    int i = base + threadIdx.x;
    int v = (i < N_NODES) ? cnt[i] : 0;
    buf[threadIdx.x] = v;
    __syncthreads();
    for (int off = 1; off < 1024; off <<= 1) {
      int tv = (threadIdx.x >= off) ? buf[threadIdx.x - off] : 0;
      __syncthreads();
      buf[threadIdx.x] += tv;
      __syncthreads();
    }
    if (i < N_NODES) ptr[i] = carry + buf[threadIdx.x] - v;
    int total = buf[1023];
    __syncthreads();
    if (threadIdx.x == 0) carry += total;
    __syncthreads();
  }
  if (threadIdx.x == 0) ptr[N_NODES] = carry;
}

__global__ void k_fill(const int* __restrict__ src, const int* __restrict__ dst,
                       const int* __restrict__ ptr, int* __restrict__ cnt, int* __restrict__ col) {
  int e = blockIdx.x * blockDim.x + threadIdx.x;
  if (e < N_EDGES) {
    int d = dst[e];
    int pos = atomicAdd(&cnt[d], 1);
    col[ptr[d] + pos] = src[e];
  }
}

__global__ void k_avglog(const int* __restrict__ degall, float* __restrict__ scal) {
  __shared__ float L[256];
  float s = 0.f;
  for (int n = blockIdx.x * blockDim.x + threadIdx.x; n < N_NODES; n += gridDim.x * blockDim.x)
    s += logf((float)degall[n] + 1.0f);
  L[threadIdx.x] = s;
  __syncthreads();
  for (int o = 128; o > 0; o >>= 1) {
    if (threadIdx.x < o) L[threadIdx.x] += L[threadIdx.x + o];
    __syncthreads();
  }
  if (threadIdx.x == 0) atomicAdd(&scal[0], L[0]);
}

__global__ void k_avg_fin(float* scal) {
  float avg = scal[0] / (float)N_NODES;
  scal[1] = avg;
  scal[2] = 1.0f / avg;
}

__global__ void k_scalars(const int* __restrict__ ptr, const float* __restrict__ scal,
                          float* __restrict__ a_arr, float* __restrict__ c_arr) {
  int n = blockIdx.x * blockDim.x + threadIdx.x;
  if (n < N_NODES) {
    int d = ptr[n + 1] - ptr[n];
    float degc = fmaxf((float)d, 1.f);
    float logd = logf(degc + 1.f);
    a_arr[n] = logd * scal[2];
    c_arr[n] = scal[1] / logd;
  }
}

__global__ void k_cast(const float* __restrict__ x, unsigned short* __restrict__ xb, int total) {
  int i = blockIdx.x * blockDim.x + threadIdx.x;
  if (i < total) xb[i] = f2b(x[i]);
}

// transpose + cast: out[n*K + k] = bf16(in[k*Ncol + n])
__global__ void k_tcast(const float* __restrict__ in, unsigned short* __restrict__ out,
                        int K, int Ncol) {
  int i = blockIdx.x * blockDim.x + threadIdx.x;
  if (i < K * Ncol) {
    int n = i / K, k = i % K;
    out[i] = f2b(in[(size_t)k * Ncol + n]);
  }
}

// pre-weights: BT_pre[j][k] = j<F ? Wpre[k][j] : Wpre[F+k][j-F]   (j<2F, k<F)
__global__ void k_tcast_pre(const float* __restrict__ Wpre, unsigned short* __restrict__ out, int F) {
  int i = blockIdx.x * blockDim.x + threadIdx.x;
  if (i < 2 * F * F) {
    int j = i / F, k = i % F;
    float v = (j < F) ? Wpre[(size_t)k * F + j] : Wpre[(size_t)(F + k) * F + (j - F)];
    out[i] = f2b(v);
  }
}

__global__ void k_biaspre(const float* __restrict__ bpre, float* __restrict__ biasPre, int F) {
  int j = threadIdx.x;
  if (j < 2 * F) biasPre[j] = (j < F) ? bpre[j] : 0.f;
}

// ---------------- fp32 GEMM (tiny, weights-only): C[M,Ncol] = A@B ----------------
__global__ __launch_bounds__(256) void k_gemm_f32(const float* __restrict__ A, const float* __restrict__ B,
                                                  float* __restrict__ C, int M, int Ncol, int K) {
  __shared__ float As[16][136];
  __shared__ float Bs[16][128];
  int tid = threadIdx.x;
  int row0 = blockIdx.y * 128, col0 = blockIdx.x * 128;
  int am = tid >> 1, ah = (tid & 1) * 8;
  int ty = tid >> 4, tx = tid & 15;
  float acc[8][8];
#pragma unroll
  for (int i = 0; i < 8; i++)
#pragma unroll
    for (int j = 0; j < 8; j++) acc[i][j] = 0.f;
  int arow = row0 + am;
  bool av = arow < M;
  const float* Ar = A + (size_t)arow * K;
  for (int k0 = 0; k0 < K; k0 += 16) {
    float4 a0 = make_float4(0, 0, 0, 0), a1 = make_float4(0, 0, 0, 0);
    if (av) {
      a0 = *(const float4*)(Ar + k0 + ah);
      a1 = *(const float4*)(Ar + k0 + ah + 4);
    }
    As[ah + 0][am] = a0.x; As[ah + 1][am] = a0.y; As[ah + 2][am] = a0.z; As[ah + 3][am] = a0.w;
    As[ah + 4][am] = a1.x; As[ah + 5][am] = a1.y; As[ah + 6][am] = a1.z; As[ah + 7][am] = a1.w;
#pragma unroll
    for (int i = 0; i < 2; i++) {
      int q = tid * 2 + i;
      int kk = q >> 5, j4 = (q & 31) * 4;
      int bc = col0 + j4;
      float4 b = make_float4(0, 0, 0, 0);
      if (bc < Ncol) b = *(const float4*)(B + (size_t)(k0 + kk) * Ncol + bc);
      *(float4*)(&Bs[kk][j4]) = b;
    }
    __syncthreads();
#pragma unroll
    for (int kk = 0; kk < 16; kk++) {
      float av8[8], bv8[8];
#pragma unroll
      for (int i = 0; i < 8; i++) av8[i] = As[kk][ty * 8 + i];
#pragma unroll
      for (int j = 0; j < 8; j++) bv8[j] = Bs[kk][tx * 8 + j];
#pragma unroll
      for (int i = 0; i < 8; i++)
#pragma unroll
        for (int j = 0; j < 8; j++) acc[i][j] = fmaf(av8[i], bv8[j], acc[i][j]);
    }
    __syncthreads();
  }
#pragma unroll
  for (int i = 0; i < 8; i++) {
    int r = row0 + ty * 8 + i;
    if (r < M) {
#pragma unroll
      for (int j = 0; j < 8; j++) {
        int c = col0 + tx * 8 + j;
        if (c < Ncol) C[(size_t)r * Ncol + c] = acc[i][j];
      }
    }
  }
}

// ---------------- fused MFMA tile kernel ----------------
// NPH=1 (GEN): C[n0+r, :] = A[r,:K] @ BT^T + bias
// NPH=3 (POST): A rows are [x | mean|min|max|std] (5F). K-loop over 5F; for k>=F the
// staged A-tile feeds 3 B slices (k, k+4F, k+8F); result = acc0 + an*acc1 + cn*acc2 + bias.
template <int NTILE, int WM, int WN, int NPH, typename To>
__global__ __launch_bounds__(256) void k_tile(
    const unsigned short* __restrict__ A, int lda, int kext, int Fdim,
    const unsigned short* __restrict__ BT, int KB,
    const float* __restrict__ a_arr, const float* __restrict__ c_arr,
    const float* __restrict__ bias,
    To* __restrict__ C, int n0, int M, int Ncol) {
  constexpr int MTILE = WM * 32;
  constexpr int PK = 40;  // 80B rows: 16B-aligned frags, spread bank pattern
  __shared__ unsigned short As[MTILE][PK];
  __shared__ unsigned short Bs[NPH][NTILE][PK];
  const int tid = threadIdx.x;
  const int lane = tid & 63;
  const int wid = tid >> 6;
  const int wr = wid / WN;
  const int wc = wid % WN;
  const int row0 = blockIdx.y * MTILE;
  const int col0 = blockIdx.x * NTILE;
  const int l15 = lane & 15, lq = lane >> 4;
  const int lk8 = lq * 8;
  constexpr int CA = MTILE / 64;
  constexpr int CB = NTILE / 64;
  uint4 apf[CA], bpf[NPH][CB];
  f32x4 acc[NPH][2][4];
#pragma unroll
  for (int p = 0; p < NPH; p++)
#pragma unroll
    for (int m = 0; m < 2; m++)
#pragma unroll
      for (int n = 0; n < 4; n++) acc[p][m][n] = (f32x4){0.f, 0.f, 0.f, 0.f};

  auto npf = [&](int k0) -> int { return (NPH == 1 || k0 < Fdim) ? 1 : NPH; };
  auto load = [&](int k0, int np) {
#pragma unroll
    for (int i = 0; i < CA; i++) {
      int idx = tid + 256 * i;
      int r = idx >> 2, c16 = idx & 3;
      int gr = row0 + r;
      uint4 v = make_uint4(0u, 0u, 0u, 0u);
      if (gr < M) v = *(const uint4*)(A + (size_t)gr * lda + k0 + c16 * 8);
      apf[i] = v;
    }
#pragma unroll
    for (int p = 0; p < NPH; p++) {
      if (p < np) {
#pragma unroll
        for (int i = 0; i < CB; i++) {
          int idx = tid + 256 * i;
          int r = idx >> 2, c16 = idx & 3;
          bpf[p][i] = *(const uint4*)(BT + (size_t)(col0 + r) * KB + k0 + p * 4 * Fdim + c16 * 8);
        }
      }
    }
  };

  load(0, npf(0));
  for (int k0 = 0; k0 < kext; k0 += 32) {
    const int np = npf(k0);
#pragma unroll
    for (int i = 0; i < CA; i++) {
      int idx = tid + 256 * i;
      *(uint4*)&As[idx >> 2][(idx & 3) * 8] = apf[i];
    }
#pragma unroll
    for (int p = 0; p < NPH; p++) {
      if (p < np) {
#pragma unroll
        for (int i = 0; i < CB; i++) {
          int idx = tid + 256 * i;
          *(uint4*)&Bs[p][idx >> 2][(idx & 3) * 8] = bpf[p][i];
        }
      }
    }
    __syncthreads();
    if (k0 + 32 < kext) load(k0 + 32, npf(k0 + 32));  // prefetch hidden under MFMA
    bf16x8 af0 = *(const bf16x8*)&As[wr * 32 + l15][lk8];
    bf16x8 af1 = *(const bf16x8*)&As[wr * 32 + 16 + l15][lk8];
#pragma unroll
    for (int p = 0; p < NPH; p++) {
      if (p < np) {
#pragma unroll
        for (int n = 0; n < 4; n++) {
          bf16x8 bf = *(const bf16x8*)&Bs[p][wc * 64 + n * 16 + l15][lk8];
          acc[p][0][n] = __builtin_amdgcn_mfma_f32_16x16x32_bf16(af0, bf, acc[p][0][n], 0, 0, 0);
          acc[p][1][n] = __builtin_amdgcn_mfma_f32_16x16x32_bf16(af1, bf, acc[p][1][n], 0, 0, 0);
        }
      }
    }
    __syncthreads();
  }
  // epilogue: fold scales, add bias, store (C/D map: col=lane&15, row=lq*4+j)
#pragma unroll
  for (int m = 0; m < 2; m++) {
    f32x4 anv = (f32x4){0.f, 0.f, 0.f, 0.f}, cnv = anv;
    if (NPH == 3) {
#pragma unroll
      for (int j = 0; j < 4; j++) {
        int r = row0 + wr * 32 + m * 16 + lq * 4 + j;
        if (r < M) { anv[j] = a_arr[n0 + r]; cnv[j] = c_arr[n0 + r]; }
      }
    }
#pragma unroll
    for (int n = 0; n < 4; n++) {
      f32x4 v = acc[0][m][n];
      if (NPH == 3) v += anv * acc[1][m][n] + cnv * acc[2][m][n];
      int col = col0 + wc * 64 + n * 16 + l15;
      float bv = bias ? bias[col] : 0.f;
#pragma unroll
      for (int j = 0; j < 4; j++) {
        int r = row0 + wr * 32 + m * 16 + lq * 4 + j;
        if (r < M) stv(&C[(size_t)(n0 + r) * Ncol + col], v[j] + bv);
      }
    }
  }
}

// ---------------- edge aggregation: writes aggx chunk rows [x | mean|min|max|std] ----------------
template <int F>
__global__ __launch_bounds__(256) void k_edge_agg(const unsigned short* __restrict__ ts,
                                                  const unsigned short* __restrict__ xin,
                                                  const int* __restrict__ ptr, const int* __restrict__ col,
                                                  unsigned short* __restrict__ aggx, int n0, int nchunk) {
  constexpr int R = F / 64;
  int idx = (blockIdx.x * blockDim.x + threadIdx.x) >> 6;
  int lane = threadIdx.x & 63;
  if (idx >= nchunk) return;
  int n = n0 + idx;
  if (n >= N_NODES) return;
  size_t obase = (size_t)idx * 5 * F;
  // x copy into slot 0
#pragma unroll
  for (int r = 0; r < R; r++)
    aggx[obase + lane + 64 * r] = xin[(size_t)n * F + lane + 64 * r];
  float S1[R], S2[R], mn[R], mx[R];
#pragma unroll
  for (int r = 0; r < R; r++) {
    S1[r] = 0.f; S2[r] = 0.f;
    mn[r] = 3.4e38f; mx[r] = -3.4e38f;
  }
  int e0 = ptr[n], e1 = ptr[n + 1];
  for (int e = e0; e < e1; ++e) {
    int sidx = col[e];
    const unsigned short* srow = ts + (size_t)sidx * 2 * F + F;  // s part
#pragma unroll
    for (int r = 0; r < R; r++) {
      float v = b2f(srow[lane + 64 * r]);
      S1[r] += v;
      S2[r] += v * v;
      mn[r] = fminf(mn[r], v);
      mx[r] = fmaxf(mx[r], v);
    }
  }
  int d = e1 - e0;
#pragma unroll
  for (int r = 0; r < R; r++) {
    float mean, sd, lo, hi;
    if (d > 0) {
      float inv = 1.f / (float)d;
      float ms = S1[r] * inv;
      float var = fmaxf(S2[r] * inv - ms * ms, 0.f);
      sd = sqrtf(var + 1e-5f);
      float tv = b2f(ts[(size_t)n * 2 * F + lane + 64 * r]);  // t part
      mean = tv + ms;
      lo = tv + mn[r];
      hi = tv + mx[r];
    } else {
      mean = 0.f; lo = 0.f; hi = 0.f;
      sd = sqrtf(1e-5f);
    }
    size_t b = obase + F + lane + 64 * r;
    aggx[b] = f2b(mean);
    aggx[b + F] = f2b(lo);
    aggx[b + 2 * F] = f2b(hi);
    aggx[b + 3 * F] = f2b(sd);
  }
}

// ---------------- BN ----------------
template <int FO, typename Ti>
__global__ __launch_bounds__(256) void k_bn_stats(const Ti* __restrict__ o, float* __restrict__ gsum,
                                                  float* __restrict__ gsq) {
  constexpr int P = 256 / FO;
  int c = threadIdx.x % FO;
  int p = threadIdx.x / FO;
  float s1 = 0.f, s2 = 0.f;
  for (int n = blockIdx.x * P + p; n < N_NODES; n += gridDim.x * P) {
    float v = ldf(o[(size_t)n * FO + c]);
    s1 += v;
    s2 += v * v;
  }
  __shared__ float L1[256], L2[256];
  L1[threadIdx.x] = s1;
  L2[threadIdx.x] = s2;
  __syncthreads();
  if (p == 0) {
#pragma unroll
    for (int q = 1; q < P; q++) {
      s1 += L1[q * FO + c];
      s2 += L2[q * FO + c];
    }
    atomicAdd(&gsum[c], s1);
    atomicAdd(&gsq[c], s2);
  }
}

__global__ void k_bn_fin(const float* bnsum, const float* bnsq, float* bnmean, float* bnrs, int FO) {
  int c = threadIdx.x;
  if (c < FO) {
    float mean = bnsum[c] / (float)N_NODES;
    float var = bnsq[c] / (float)N_NODES - mean * mean;
    bnmean[c] = mean;
    bnrs[c] = rsqrtf(var + 1e-5f);
  }
}

template <typename Ti>
__global__ void k_bn_elu(const Ti* __restrict__ o, const float* __restrict__ mean,
                         const float* __restrict__ rs, const float* __restrict__ gamma,
                         const float* __restrict__ beta, unsigned short* __restrict__ h,
                         float* __restrict__ bnout, int FO) {
  int idx = blockIdx.x * blockDim.x + threadIdx.x;
  if (idx < N_NODES * FO) {
    int c = idx % FO;
    float y = gamma[c] * (ldf(o[idx]) - mean[c]) * rs[c] + beta[c];
    if (bnout) bnout[idx] = y;
    h[idx] = f2b(y > 0.f ? y : expm1f(y));
  }
}

// ---------------- misc ----------------
__global__ void k_bcomb(const float* __restrict__ bpost, const float* __restrict__ Wlin,
                        const float* __restrict__ blin, float* __restrict__ bcomb, int FO) {
  int j = threadIdx.x;
  if (j < FO) {
    float acc = blin[j];
    for (int k = 0; k < FO; k++) acc += bpost[k] * Wlin[k * FO + j];
    bcomb[j] = acc;
  }
}

__global__ void k_add(const unsigned short* __restrict__ a, const unsigned short* __restrict__ b,
                      unsigned short* __restrict__ c) {
  int idx = blockIdx.x * blockDim.x + threadIdx.x;
  if (idx < N_NODES * 128) c[idx] = f2b(b2f(a[idx]) + b2f(b[idx]));
}

__global__ void k_logits(const unsigned short* __restrict__ h4, const float* __restrict__ Wc,
                         const float* __restrict__ bc, float* __restrict__ out) {
  int n = blockIdx.x * blockDim.x + threadIdx.x;
  if (n < N_NODES) {
    float acc0 = bc[0], acc1 = bc[1];
    const unsigned short* hr = h4 + (size_t)n * 64;
    for (int k = 0; k < 64; k++) {
      float v = b2f(hr[k]);
      acc0 += v * Wc[k * 2 + 0];
      acc1 += v * Wc[k * 2 + 1];
    }
    out[n * 2 + 0] = acc0;
    out[n * 2 + 1] = acc1;
  }
}

// ---------------- driver ----------------
struct WS {
  int *ptr, *col, *cnt, *degall;
  float *scal, *a_arr, *c_arr, *bnsum, *bnsq, *bnmean, *bnrs, *wcomb, *bcomb, *biasPre;
  unsigned short *wcombT, *wpreT;
  unsigned short *xb, *h1, *h2, *h3, *ts, *aggx;
  size_t agg_elems;
};

template <int F, typename To>
static void run_layer(const unsigned short* xin, To* o_ptr, float* bnout, unsigned short* hout,
                      const float* Wpre, const float* bpre, const float* Wpost, const float* bpost,
                      const float* Wlin, const float* blin, const float* gamma, const float* beta,
                      int FO, const WS& ws, hipStream_t stream) {
  const int N = N_NODES;
  const int K13 = 13 * F;
  // weight prep
  {
    dim3 g((FO + 127) / 128, (K13 + 127) / 128);
    k_gemm_f32<<<g, 256, 0, stream>>>(Wpost, Wlin, ws.wcomb, K13, FO, FO);
    k_bcomb<<<1, 256, 0, stream>>>(bpost, Wlin, blin, ws.bcomb, FO);
    k_tcast<<<(K13 * FO + 255) / 256, 256, 0, stream>>>(ws.wcomb, ws.wcombT, K13, FO);
    k_tcast_pre<<<(2 * F * F + 255) / 256, 256, 0, stream>>>(Wpre, ws.wpreT, F);
    k_biaspre<<<1, 512, 0, stream>>>(bpre, ws.biasPre, F);
  }
  // fused pre-GEMM: ts = xin @ [W1 | W2] + [bpre | 0]
  {
    dim3 g(2 * F / 128, (N + 63) / 64);
    k_tile<128, 2, 2, 1, unsigned short><<<g, 256, 0, stream>>>(
        xin, F, F, F, ws.wpreT, F, nullptr, nullptr, ws.biasPre, ws.ts, 0, N, 2 * F);
  }
  // chunked: edge aggregation -> fused post GEMM
  int NB = (int)(ws.agg_elems / (size_t)(5 * F));
  NB &= ~63;
  if (NB > N) NB = N;
  if (NB < 64) NB = 64;
  for (int c0 = 0; c0 < N; c0 += NB) {
    int nc = (N - c0 < NB) ? (N - c0) : NB;
    k_edge_agg<F><<<(nc + 3) / 4, 256, 0, stream>>>(ws.ts, xin, ws.ptr, ws.col, ws.aggx, c0, nc);
    if (FO == 64) {
      dim3 g(1, (nc + 127) / 128);
      k_tile<64, 4, 1, 3, To><<<g, 256, 0, stream>>>(
          ws.aggx, 5 * F, 5 * F, F, ws.wcombT, K13, ws.a_arr, ws.c_arr, ws.bcomb, o_ptr, c0, nc, FO);
    } else {
      dim3 g(FO / 128, (nc + 63) / 64);
      k_tile<128, 2, 2, 3, To><<<g, 256, 0, stream>>>(
          ws.aggx, 5 * F, 5 * F, F, ws.wcombT, K13, ws.a_arr, ws.c_arr, ws.bcomb, o_ptr, c0, nc, FO);
    }
  }
  // BN + ELU
  hipMemsetAsync(ws.bnsum, 0, 256 * sizeof(float), stream);
  hipMemsetAsync(ws.bnsq, 0, 256 * sizeof(float), stream);
  if (FO == 64)
    k_bn_stats<64, To><<<128, 256, 0, stream>>>(o_ptr, ws.bnsum, ws.bnsq);
  else if (FO == 128)
    k_bn_stats<128, To><<<128, 256, 0, stream>>>(o_ptr, ws.bnsum, ws.bnsq);
  else
    k_bn_stats<256, To><<<128, 256, 0, stream>>>(o_ptr, ws.bnsum, ws.bnsq);
  k_bn_fin<<<1, 256, 0, stream>>>(ws.bnsum, ws.bnsq, ws.bnmean, ws.bnrs, FO);
  int total = N_NODES * FO;
  k_bn_elu<To><<<(total + 255) / 256, 256, 0, stream>>>(o_ptr, ws.bnmean, ws.bnrs, gamma, beta, hout, bnout, FO);
}

extern "C" void kernel_launch(void* const* d_in, const int* in_sizes, int n_in,
                              void* d_out, int out_size, void* d_ws, size_t ws_size,
                              hipStream_t stream) {
  const int N = N_NODES, E = N_EDGES;
  const float* x = (const float*)d_in[0];
  const int* ei = (const int*)d_in[1];
  const int* src = ei;
  const int* dst = ei + E;
  const float *Wpre[4], *bpre[4], *Wpost[4], *bpost[4], *Wlin[4], *blin[4], *gamma[4], *beta[4];
  for (int i = 0; i < 4; i++) {
    const int b = 2 + i * 8;
    Wpre[i] = (const float*)d_in[b + 0];
    bpre[i] = (const float*)d_in[b + 1];
    Wpost[i] = (const float*)d_in[b + 2];
    bpost[i] = (const float*)d_in[b + 3];
    Wlin[i] = (const float*)d_in[b + 4];
    blin[i] = (const float*)d_in[b + 5];
    gamma[i] = (const float*)d_in[b + 6];
    beta[i] = (const float*)d_in[b + 7];
  }
  const float* Wc = (const float*)d_in[34];
  const float* bcv = (const float*)d_in[35];

  // ----- workspace layout (~109 MB fixed + adaptive aggx) -----
  char* w = (char*)d_ws;
  size_t off = 0;
  auto alloc = [&](size_t bytes) -> void* {
    void* p = (void*)(w + off);
    off = (off + bytes + 255) & ~(size_t)255;
    return p;
  };
  WS ws;
  ws.ptr = (int*)alloc((N + 1) * sizeof(int));
  ws.col = (int*)alloc((size_t)E * sizeof(int));
  ws.cnt = (int*)alloc((size_t)N * sizeof(int));
  ws.degall = (int*)alloc((size_t)N * sizeof(int));
  ws.scal = (float*)alloc(16 * sizeof(float));
  ws.a_arr = (float*)alloc((size_t)N * sizeof(float));
  ws.c_arr = (float*)alloc((size_t)N * sizeof(float));
  ws.bnsum = (float*)alloc(256 * sizeof(float));
  ws.bnsq = (float*)alloc(256 * sizeof(float));
  ws.bnmean = (float*)alloc(256 * sizeof(float));
  ws.bnrs = (float*)alloc(256 * sizeof(float));
  ws.wcomb = (float*)alloc((size_t)13 * 256 * 128 * sizeof(float));
  ws.bcomb = (float*)alloc(256 * sizeof(float));
  ws.biasPre = (float*)alloc(512 * sizeof(float));
  ws.wcombT = (unsigned short*)alloc((size_t)13 * 256 * 128 * sizeof(unsigned short));
  ws.wpreT = (unsigned short*)alloc((size_t)512 * 256 * sizeof(unsigned short));
  ws.xb = (unsigned short*)alloc((size_t)N * 128 * sizeof(unsigned short));
  ws.h1 = (unsigned short*)alloc((size_t)N * 128 * sizeof(unsigned short));
  ws.h2 = (unsigned short*)alloc((size_t)N * 256 * sizeof(unsigned short));
  ws.h3 = (unsigned short*)alloc((size_t)N * 128 * sizeof(unsigned short));
  ws.ts = (unsigned short*)alloc((size_t)N * 512 * sizeof(unsigned short));
  size_t rem = (ws_size > off) ? (ws_size - off) : 0;
  ws.agg_elems = rem / sizeof(unsigned short);
  ws.aggx = (unsigned short*)(w + off);
  unsigned short* h4 = ws.xb;  // alias: x dead after layer 1; h4 is [N,64]

  float* outp = (float*)d_out;
  float* logits = outp;              // [N,2]
  float* p4 = outp + (size_t)N * 2;  // [N,64]
  float* b4 = p4 + (size_t)N * 64;   // [N,64]
  unsigned short* o_scratch = (unsigned short*)p4;  // pre-BN scratch, overwritten by layer 4

  // ----- degree / CSR / scalars -----
  hipMemsetAsync(ws.cnt, 0, N * sizeof(int), stream);
  hipMemsetAsync(ws.degall, 0, N * sizeof(int), stream);
  hipMemsetAsync(ws.scal, 0, 16 * sizeof(float), stream);
  k_count<<<(E + 255) / 256, 256, 0, stream>>>(src, dst, ws.cnt, ws.degall);
  k_scan<<<1, 1024, 0, stream>>>(ws.cnt, ws.ptr);
  hipMemsetAsync(ws.cnt, 0, N * sizeof(int), stream);
  k_fill<<<(E + 255) / 256, 256, 0, stream>>>(src, dst, ws.ptr, ws.cnt, ws.col);
  k_avglog<<<64, 256, 0, stream>>>(ws.degall, ws.scal);
  k_avg_fin<<<1, 1, 0, stream>>>(ws.scal);
  k_scalars<<<(N + 255) / 256, 256, 0, stream>>>(ws.ptr, ws.scal, ws.a_arr, ws.c_arr);
  k_cast<<<(N * 128 + 255) / 256, 256, 0, stream>>>(x, ws.xb, N * 128);

  run_layer<128, unsigned short>(ws.xb, o_scratch, nullptr, ws.h1,
                                 Wpre[0], bpre[0], Wpost[0], bpost[0], Wlin[0], blin[0], gamma[0], beta[0],
                                 128, ws, stream);
  run_layer<128, unsigned short>(ws.h1, o_scratch, nullptr, ws.h2,
                                 Wpre[1], bpre[1], Wpost[1], bpost[1], Wlin[1], blin[1], gamma[1], beta[1],
                                 256, ws, stream);
  run_layer<256, unsigned short>(ws.h2, o_scratch, nullptr, ws.h3,
                                 Wpre[2], bpre[2], Wpost[2], bpost[2], Wlin[2], blin[2], gamma[2], beta[2],
                                 128, ws, stream);
  k_add<<<((N * 128) + 255) / 256, 256, 0, stream>>>(ws.h1, ws.h3, ws.h3);  // x4 = h1 + h3 in place
  run_layer<128, float>(ws.h3, p4, b4, h4,
                        Wpre[3], bpre[3], Wpost[3], bpost[3], Wlin[3], blin[3], gamma[3], beta[3],
                        64, ws, stream);
  k_logits<<<(N + 255) / 256, 256, 0, stream>>>(h4, Wc, bcv, logits);
  (void)in_sizes; (void)n_in; (void)out_size; (void)ws_size;
}